// Round 3
// baseline (363.583 us; speedup 1.0000x reference)
//
#include <hip/hip_runtime.h>
#include <math.h>

static constexpr int BB  = 4;
static constexpr int HH  = 1024;
static constexpr int WW  = 1024;
static constexpr int HWP = HH * WW;       // 1<<20
static constexpr int NPIX = BB * HWP;     // 4<<20
static constexpr int ROUNDS = 24;

__device__ __forceinline__ int reflect_idx(int i, int n) {
    i = (i < 0) ? -i : i;                 // jnp.pad mode='reflect': -1 -> 1
    return (i >= n) ? (2 * n - 2 - i) : i;
}

// ---------------- grayscale (f64) ----------------
__global__ void k_gray(const float* __restrict__ x, double* __restrict__ gray) {
    int i = blockIdx.x * blockDim.x + threadIdx.x;
    if (i >= NPIX) return;
    int b = i >> 20;
    int p = i & (HWP - 1);
    const float* base = x + (size_t)b * 3u * HWP;
    double r  = (double)base[p];
    double g  = (double)base[HWP + p];
    double bl = (double)base[2 * HWP + p];
    gray[i] = r * 0.299 + g * 0.587 + bl * 0.114;
}

// ---------------- separable gaussian blur, reflect padding (f64) ----------------
__global__ void k_hblur(const double* __restrict__ in, double* __restrict__ out,
                        double w0, double w1, double w2) {
    int i = blockIdx.x * blockDim.x + threadIdx.x;
    if (i >= NPIX) return;
    int xc = i & (WW - 1);
    int rowbase = i - xc;
    double s;
    s  = w0 * in[rowbase + reflect_idx(xc - 2, WW)];
    s += w1 * in[rowbase + reflect_idx(xc - 1, WW)];
    s += w2 * in[rowbase + xc];
    s += w1 * in[rowbase + reflect_idx(xc + 1, WW)];
    s += w0 * in[rowbase + reflect_idx(xc + 2, WW)];
    out[i] = s;
}

__global__ void k_vblur(const double* __restrict__ in, double* __restrict__ out,
                        double w0, double w1, double w2) {
    int i = blockIdx.x * blockDim.x + threadIdx.x;
    if (i >= NPIX) return;
    int xc = i & (WW - 1);
    int y  = (i >> 10) & (HH - 1);
    int b  = i >> 20;
    const double* img = in + (size_t)b * HWP;
    double s;
    s  = w0 * img[reflect_idx(y - 2, HH) * WW + xc];
    s += w1 * img[reflect_idx(y - 1, HH) * WW + xc];
    s += w2 * img[y * WW + xc];
    s += w1 * img[reflect_idx(y + 1, HH) * WW + xc];
    s += w0 * img[reflect_idx(y + 2, HH) * WW + xc];
    out[i] = s;
}

// ---------------- sobel + magnitude + quantized direction (f64) ----------------
__global__ void k_sobel(const double* __restrict__ bl, double* __restrict__ mag,
                        unsigned char* __restrict__ dir) {
    int i = blockIdx.x * blockDim.x + threadIdx.x;
    if (i >= NPIX) return;
    int xc = i & (WW - 1);
    int y  = (i >> 10) & (HH - 1);
    int b  = i >> 20;
    const double* img = bl + (size_t)b * HWP;
    int xm = xc > 0 ? xc - 1 : 0;
    int xp = xc < WW - 1 ? xc + 1 : WW - 1;   // replicate ('edge') padding
    int ym = y > 0 ? y - 1 : 0;
    int yp = y < HH - 1 ? y + 1 : HH - 1;
    double b00 = img[ym * WW + xm], b01 = img[ym * WW + xc], b02 = img[ym * WW + xp];
    double b10 = img[y  * WW + xm],                          b12 = img[y  * WW + xp];
    double b20 = img[yp * WW + xm], b21 = img[yp * WW + xc], b22 = img[yp * WW + xp];
    double gx = -b00 + b02 - 2.0 * b10 + 2.0 * b12 - b20 + b22;
    double gy = -b00 - 2.0 * b01 - b02 + b20 + 2.0 * b21 + b22;
    mag[i] = sqrt(gx * gx + gy * gy + 1e-6);
    double a = atan2(gy, gx) * 57.29577951308232;  // *(180/pi), f64
    a = a / 45.0;
    int ai = (int)rint(a);                          // round half-to-even, ai in [-4,4]
    dir[i] = (unsigned char)((ai + 8) & 7);         // mod 8 (nonneg)
}

// ---------------- NMS + double threshold (f64 decisions) ----------------
__global__ void k_nms(const double* __restrict__ mag, const unsigned char* __restrict__ dir,
                      float* __restrict__ out0, unsigned char* __restrict__ state) {
    int i = blockIdx.x * blockDim.x + threadIdx.x;
    if (i >= NPIX) return;
    int xc = i & (WW - 1);
    int y  = (i >> 10) & (HH - 1);
    int b  = i >> 20;
    const double* m = mag + (size_t)b * HWP;
    double c = m[y * WW + xc];
    int p = dir[i];
    // packed (d+1) 2-bit tables; dir order: 0=right, clockwise
    int dr = ((425   >> (2 * p)) & 3) - 1;
    int dc = ((36890 >> (2 * p)) & 3) - 1;
    int y1 = y + dr, x1 = xc + dc, y2 = y - dr, x2 = xc - dc;
    double mp = (y1 >= 0 && y1 < HH && x1 >= 0 && x1 < WW) ? m[y1 * WW + x1] : 0.0;
    double mn = (y2 >= 0 && y2 < HH && x2 >= 0 && x2 < WW) ? m[y2 * WW + x2] : 0.0;
    bool ismax = ((c - mp) > 0.0) && ((c - mn) > 0.0);
    double sm = ismax ? c : 0.0;
    out0[i] = (float)sm;
    state[i] = (unsigned char)((sm > 0.2) ? 2 : ((sm > 0.1) ? 1 : 0));
}

// ---------------- hysteresis: multi-launch flood-fill rounds ----------------
__global__ void k_init(int* __restrict__ flags) {
    int t = threadIdx.x;
    if (t <= ROUNDS) flags[t] = (t == 0) ? 1 : 0;   // seed: round 0 "changed"
}

__global__ void __launch_bounds__(256) k_pass(unsigned char* __restrict__ state,
                                              int* __restrict__ flags, int rr) {
    constexpr int TS = 128;
    constexpr int TH = TS + 2;
    __shared__ unsigned char s[TH][TH];
    __shared__ int s_changed;

    if (flags[rr - 1] == 0) return;       // previous round globally quiet -> converged

    const int tid  = threadIdx.x;
    const int blk  = blockIdx.x;          // 256 blocks: b(2b) | trow(3b) | tcol(3b)
    const int b    = blk >> 6;
    const int trow = (blk >> 3) & 7;
    const int tcol = blk & 7;
    const int oy = trow * TS;
    const int ox = tcol * TS;
    const int lx = tid & (TS - 1);
    const int rg = tid >> 7;              // 0 or 1
    unsigned char* st = state + (size_t)b * HWP;

    // load tile + 1px halo (zero outside image = conv zero padding)
    for (int idx = tid; idx < TH * TH; idx += 256) {
        int sy = idx / TH, sx = idx - sy * TH;
        int gy = oy + sy - 1, gx = ox + sx - 1;
        unsigned char v = 0;
        if (gy >= 0 && gy < HH && gx >= 0 && gx < WW)
            v = st[(size_t)gy * WW + gx];
        s[sy][sx] = v;
    }
    __syncthreads();

    // local fixed point: weak(1) with any strong(2) 8-neighbor -> strong
    int blockChanged = 0;
    for (;;) {
        if (tid == 0) s_changed = 0;
        __syncthreads();
        int changed = 0;
        for (int k = 0; k < TS / 2; ++k) {
            int r = rg + 2 * k;
            if (s[r + 1][lx + 1] == 1) {
                bool up = (s[r][lx] == 2) | (s[r][lx + 1] == 2) | (s[r][lx + 2] == 2) |
                          (s[r + 1][lx] == 2) | (s[r + 1][lx + 2] == 2) |
                          (s[r + 2][lx] == 2) | (s[r + 2][lx + 1] == 2) | (s[r + 2][lx + 2] == 2);
                if (up) { s[r + 1][lx + 1] = 2; changed = 1; }
            }
        }
        if (changed) s_changed = 1;       // benign shared race: all writers store 1
        __syncthreads();
        if (!s_changed) break;
        blockChanged = 1;
        __syncthreads();                  // separate break-read from next-pass reset
    }

    if (blockChanged) {
        for (int k = 0; k < TS / 2; ++k) {
            int r = rg + 2 * k;
            st[(size_t)(oy + r) * WW + ox + lx] = s[r + 1][lx + 1];
        }
        if (tid == 0) atomicOr(&flags[rr], 1);   // device-scope by default
    }
}

__global__ void k_edges(const unsigned char* __restrict__ state, float* __restrict__ out1) {
    int i = blockIdx.x * blockDim.x + threadIdx.x;
    if (i >= NPIX) return;
    out1[i] = (state[i] == 2) ? 1.0f : 0.0f;
}

extern "C" void kernel_launch(void* const* d_in, const int* in_sizes, int n_in,
                              void* d_out, int out_size, void* d_ws, size_t ws_size,
                              hipStream_t stream) {
    const float* x = (const float*)d_in[0];
    float* out0 = (float*)d_out;          // suppressed magnitude [4,1,1024,1024]
    float* out1 = out0 + NPIX;            // edges [4,1,1024,1024]

    // workspace layout: A (N f64) | Bf (N f64) | dir (N u8) | flags
    // state (N u8) aliases A (dead after k_sobel).
    double* A  = (double*)d_ws;
    double* Bf = A + NPIX;
    unsigned char* dir   = (unsigned char*)(Bf + NPIX);
    unsigned char* state = (unsigned char*)d_ws;     // alias of A
    int* flags = (int*)(dir + NPIX);

    // gaussian weights, f64 ops mirroring the reference
    double g0 = exp(-2.0), g1 = exp(-0.5), g2 = 1.0;
    double sum = (((g0 + g1) + g2) + g1) + g0;
    double w0 = g0 / sum, w1 = g1 / sum, w2 = g2 / sum;

    dim3 blk(256), grd(NPIX / 256);
    k_gray <<<grd, blk, 0, stream>>>(x, A);
    k_hblur<<<grd, blk, 0, stream>>>(A, Bf, w0, w1, w2);
    k_vblur<<<grd, blk, 0, stream>>>(Bf, A, w0, w1, w2);
    k_sobel<<<grd, blk, 0, stream>>>(A, Bf, dir);
    k_nms  <<<grd, blk, 0, stream>>>(Bf, dir, out0, state);  // state overwrites A region

    k_init<<<1, 64, 0, stream>>>(flags);
    for (int r = 1; r <= ROUNDS; ++r)
        k_pass<<<dim3(BB * 64), blk, 0, stream>>>(state, flags, r);
    k_edges<<<grd, blk, 0, stream>>>(state, out1);
}

// Round 4
// 198.854 us; speedup vs baseline: 1.8284x; 1.8284x over previous
//
#include <hip/hip_runtime.h>
#include <math.h>

static constexpr int BB  = 4;
static constexpr int HH  = 1024;
static constexpr int WW  = 1024;
static constexpr int HWP = HH * WW;       // 1<<20
static constexpr int NPIX = BB * HWP;     // 4<<20
static constexpr int WPR = WW / 64;       // 16 words per image row
static constexpr int PW  = HWP / 64;      // 16384 words per image bitplane
static constexpr int ROUNDS = 16;

__device__ __forceinline__ int reflect_idx(int i, int n) {
    i = (i < 0) ? -i : i;                 // jnp.pad mode='reflect': -1 -> 1
    return (i >= n) ? (2 * n - 2 - i) : i;
}

// ---------------- fused grayscale + horizontal gaussian (f64), reflect pad ----------------
__global__ void k_hgray(const float* __restrict__ x, double* __restrict__ out,
                        double w0, double w1, double w2) {
    int i = blockIdx.x * blockDim.x + threadIdx.x;
    if (i >= NPIX) return;
    int xc = i & (WW - 1);
    int y  = (i >> 10) & (HH - 1);
    int b  = i >> 20;
    const float* base = x + (size_t)b * 3u * HWP + (size_t)y * WW;
    auto gr = [&](int xx) -> double {
        double r  = (double)base[xx];
        double g  = (double)base[HWP + xx];
        double bl = (double)base[2 * HWP + xx];
        return r * 0.299 + g * 0.587 + bl * 0.114;
    };
    double s;
    s  = w0 * gr(reflect_idx(xc - 2, WW));
    s += w1 * gr(reflect_idx(xc - 1, WW));
    s += w2 * gr(xc);
    s += w1 * gr(reflect_idx(xc + 1, WW));
    s += w0 * gr(reflect_idx(xc + 2, WW));
    out[i] = s;
}

// ---------------- vertical gaussian (f64), reflect pad ----------------
__global__ void k_vblur(const double* __restrict__ in, double* __restrict__ out,
                        double w0, double w1, double w2) {
    int i = blockIdx.x * blockDim.x + threadIdx.x;
    if (i >= NPIX) return;
    int xc = i & (WW - 1);
    int y  = (i >> 10) & (HH - 1);
    int b  = i >> 20;
    const double* img = in + (size_t)b * HWP;
    double s;
    s  = w0 * img[reflect_idx(y - 2, HH) * WW + xc];
    s += w1 * img[reflect_idx(y - 1, HH) * WW + xc];
    s += w2 * img[y * WW + xc];
    s += w1 * img[reflect_idx(y + 1, HH) * WW + xc];
    s += w0 * img[reflect_idx(y + 2, HH) * WW + xc];
    out[i] = s;
}

// ---------------- sobel + magnitude + quantized direction (f64) ----------------
__global__ void k_sobel(const double* __restrict__ bl, double* __restrict__ mag,
                        unsigned char* __restrict__ dir) {
    int i = blockIdx.x * blockDim.x + threadIdx.x;
    if (i >= NPIX) return;
    int xc = i & (WW - 1);
    int y  = (i >> 10) & (HH - 1);
    int b  = i >> 20;
    const double* img = bl + (size_t)b * HWP;
    int xm = xc > 0 ? xc - 1 : 0;
    int xp = xc < WW - 1 ? xc + 1 : WW - 1;   // replicate ('edge') padding
    int ym = y > 0 ? y - 1 : 0;
    int yp = y < HH - 1 ? y + 1 : HH - 1;
    double b00 = img[ym * WW + xm], b01 = img[ym * WW + xc], b02 = img[ym * WW + xp];
    double b10 = img[y  * WW + xm],                          b12 = img[y  * WW + xp];
    double b20 = img[yp * WW + xm], b21 = img[yp * WW + xc], b22 = img[yp * WW + xp];
    double gx = -b00 + b02 - 2.0 * b10 + 2.0 * b12 - b20 + b22;
    double gy = -b00 - 2.0 * b01 - b02 + b20 + 2.0 * b21 + b22;
    mag[i] = sqrt(gx * gx + gy * gy + 1e-6);
    double a = atan2(gy, gx) * 57.29577951308232;  // *(180/pi), f64
    a = a / 45.0;
    int ai = (int)rint(a);                          // round half-to-even, ai in [-4,4]
    dir[i] = (unsigned char)((ai + 8) & 7);         // mod 8 (nonneg)
}

// ---------------- NMS + double threshold -> out0 + weak/strong bitplanes ----------------
__global__ void k_nms(const double* __restrict__ mag, const unsigned char* __restrict__ dir,
                      float* __restrict__ out0,
                      unsigned long long* __restrict__ weakP,
                      unsigned long long* __restrict__ strongP) {
    int i = blockIdx.x * blockDim.x + threadIdx.x;
    if (i >= NPIX) return;
    int xc = i & (WW - 1);
    int y  = (i >> 10) & (HH - 1);
    int b  = i >> 20;
    const double* m = mag + (size_t)b * HWP;
    double c = m[y * WW + xc];
    int p = dir[i];
    // packed (d+1) 2-bit tables; dir order: 0=right, clockwise
    int dr = ((425   >> (2 * p)) & 3) - 1;
    int dc = ((36890 >> (2 * p)) & 3) - 1;
    int y1 = y + dr, x1 = xc + dc, y2 = y - dr, x2 = xc - dc;
    double mp = (y1 >= 0 && y1 < HH && x1 >= 0 && x1 < WW) ? m[y1 * WW + x1] : 0.0;
    double mn = (y2 >= 0 && y2 < HH && x2 >= 0 && x2 < WW) ? m[y2 * WW + x2] : 0.0;
    bool ismax = ((c - mp) > 0.0) && ((c - mn) > 0.0);
    double sm = ismax ? c : 0.0;
    out0[i] = (float)sm;
    bool strong = (sm > 0.2);
    bool weak   = (sm > 0.1) && !strong;
    unsigned long long wb = __ballot(weak);     // wave64: 64 consecutive x -> one word
    unsigned long long sb = __ballot(strong);
    if ((threadIdx.x & 63) == 0) {
        weakP[i >> 6]   = wb;
        strongP[i >> 6] = sb;
    }
}

// ---------------- hysteresis: bitplane flood-fill rounds ----------------
__global__ void k_init(int* __restrict__ flags) {
    int t = threadIdx.x;
    if (t <= ROUNDS) flags[t] = (t == 0) ? 1 : 0;   // seed: round 0 "changed"
}

__device__ __forceinline__ unsigned long long ks_fill(unsigned long long g, unsigned long long p) {
    // spread g through contiguous runs of p, both directions, full 64b in log steps
    unsigned long long q;
    q = p;        g |= q & (g << 1);
    q &= q << 1;  g |= q & (g << 2);
    q &= q << 2;  g |= q & (g << 4);
    q &= q << 4;  g |= q & (g << 8);
    q &= q << 8;  g |= q & (g << 16);
    q &= q << 16; g |= q & (g << 32);
    q = p;        g |= q & (g >> 1);
    q &= q >> 1;  g |= q & (g >> 2);
    q &= q >> 2;  g |= q & (g >> 4);
    q &= q >> 4;  g |= q & (g >> 8);
    q &= q >> 8;  g |= q & (g >> 16);
    q &= q >> 16; g |= q & (g >> 32);
    return g;
}

__global__ void __launch_bounds__(256) k_pass(const unsigned long long* __restrict__ weakP,
                                              unsigned long long* __restrict__ strongP,
                                              int* __restrict__ flags, int rr) {
    __shared__ unsigned long long sp[258];   // spread-form strong rows (+halo rows)
    __shared__ int s_changed;

    if (flags[rr - 1] == 0) return;          // previous round globally quiet -> converged

    const int tid = threadIdx.x;
    const int blk = blockIdx.x;              // b(2b) | ty(2b) | tx(4b): tile = 64w x 256h
    const int b  = blk >> 6;
    const int ty = (blk >> 4) & 3;
    const int tx = blk & 15;
    const int y0 = ty * 256;
    const unsigned long long* wp = weakP + (size_t)b * PW;
    unsigned long long* spl      = strongP + (size_t)b * PW;

    const int y = y0 + tid;
    const int wi = y * WPR + tx;
    unsigned long long w = wp[wi];
    unsigned long long s = spl[wi];
    unsigned long long halo_or = 0;          // static horizontal halo strong bits
    if (tx > 0)  halo_or |= (spl[wi - 1] >> 63);        // left word bit63 -> our bit0
    if (tx < WPR - 1) halo_or |= (spl[wi + 1] << 63);   // right word bit0 -> our bit63
    sp[tid + 1] = (s << 1) | s | (s >> 1) | halo_or;

    if (tid < 2) {                            // top/bottom halo rows (static this round)
        int yh = (tid == 0) ? (y0 - 1) : (y0 + 256);
        unsigned long long v = 0;
        if (yh >= 0 && yh < HH) {
            int hwi = yh * WPR + tx;
            unsigned long long hs = spl[hwi];
            v = (hs << 1) | hs | (hs >> 1);
            if (tx > 0)  v |= (spl[hwi - 1] >> 63);
            if (tx < WPR - 1) v |= (spl[hwi + 1] << 63);
        }
        sp[tid == 0 ? 0 : 257] = v;
    }

    int blockChanged = 0;
    for (;;) {
        __syncthreads();                                  // (A) sp writes + flag reads done
        if (tid == 0) s_changed = 0;
        unsigned long long up = sp[tid];
        unsigned long long dn = sp[tid + 2];
        unsigned long long own = (s << 1) | s | (s >> 1) | halo_or;
        unsigned long long g = s | (w & (up | own | dn)); // 8-conn seed step
        g = ks_fill(g, w);                                // full horizontal flood thru weak
        int ch = (g != s);
        if (ch) s = g;
        __syncthreads();                                  // (B) reads done, reset visible
        if (ch) { sp[tid + 1] = (s << 1) | s | (s >> 1) | halo_or; s_changed = 1; }
        __syncthreads();                                  // (C) writes + flag visible
        if (!s_changed) break;
        blockChanged = 1;
    }

    if (blockChanged) {
        spl[wi] = s;
        if (tid == 0) atomicOr(&flags[rr], 1);            // device-scope by default
    }
}

__global__ void k_edges(const unsigned long long* __restrict__ strongP, float* __restrict__ out1) {
    int i = blockIdx.x * blockDim.x + threadIdx.x;
    if (i >= NPIX) return;
    out1[i] = ((strongP[i >> 6] >> (i & 63)) & 1ull) ? 1.0f : 0.0f;
}

extern "C" void kernel_launch(void* const* d_in, const int* in_sizes, int n_in,
                              void* d_out, int out_size, void* d_ws, size_t ws_size,
                              hipStream_t stream) {
    const float* x = (const float*)d_in[0];
    float* out0 = (float*)d_out;          // suppressed magnitude [4,1,1024,1024]
    float* out1 = out0 + NPIX;            // edges [4,1,1024,1024]

    // workspace: A (N f64) | Bf (N f64) | dir (N u8) | weakP | strongP | flags
    double* A  = (double*)d_ws;
    double* Bf = A + NPIX;
    unsigned char* dir = (unsigned char*)(Bf + NPIX);
    unsigned long long* weakP   = (unsigned long long*)(dir + NPIX);
    unsigned long long* strongP = weakP + (size_t)BB * PW;
    int* flags = (int*)(strongP + (size_t)BB * PW);

    // gaussian weights, f64 ops mirroring the reference
    double g0 = exp(-2.0), g1 = exp(-0.5), g2 = 1.0;
    double sum = (((g0 + g1) + g2) + g1) + g0;
    double w0 = g0 / sum, w1 = g1 / sum, w2 = g2 / sum;

    dim3 blk(256), grd(NPIX / 256);
    k_hgray<<<grd, blk, 0, stream>>>(x, A, w0, w1, w2);
    k_vblur<<<grd, blk, 0, stream>>>(A, Bf, w0, w1, w2);
    k_sobel<<<grd, blk, 0, stream>>>(Bf, A, dir);           // mag into A
    k_nms  <<<grd, blk, 0, stream>>>(A, dir, out0, weakP, strongP);

    k_init<<<1, 64, 0, stream>>>(flags);
    for (int r = 1; r <= ROUNDS; ++r)
        k_pass<<<dim3(BB * 64), blk, 0, stream>>>(weakP, strongP, flags, r);
    k_edges<<<grd, blk, 0, stream>>>(strongP, out1);
}

// Round 5
// 185.705 us; speedup vs baseline: 1.9579x; 1.0708x over previous
//
#include <hip/hip_runtime.h>
#include <math.h>

static constexpr int BB  = 4;
static constexpr int HH  = 1024;
static constexpr int WW  = 1024;
static constexpr int HWP = HH * WW;       // 1<<20
static constexpr int NPIX = BB * HWP;     // 4<<20
static constexpr int WPR = WW / 64;       // 16 words per image row
static constexpr int PW  = HWP / 64;      // 16384 words per image bitplane
static constexpr int ROUNDS = 8;

// fused-stencil tile: 64 wide x 32 tall output
static constexpr int TX  = 64,  TY  = 32;
static constexpr int HBW = TX + 4;        // 68  hblur cols  (x0-2 .. x0+65)
static constexpr int HBH = TY + 8;        // 40  hblur rows  (y0-4 .. y0+35, reflected)
static constexpr int BLW = HBW;           // 68  blurred cols
static constexpr int BLH = TY + 4;        // 36  blurred rows (y0-2 .. y0+33)
static constexpr int MGW = TX + 2;        // 66  mag cols (x0-1 .. x0+64)
static constexpr int MGH = TY + 2;        // 34  mag rows (y0-1 .. y0+32)

__device__ __forceinline__ int reflect_idx(int i, int n) {
    i = (i < 0) ? -i : i;                 // jnp.pad mode='reflect': -1 -> 1
    return (i >= n) ? (2 * n - 2 - i) : i;
}

// ---------- fused: gray -> hblur -> vblur -> sobel/mag -> dir -> NMS -> ballot ----------
__global__ void __launch_bounds__(256) k_front(const float* __restrict__ x,
                                               float* __restrict__ out0,
                                               unsigned long long* __restrict__ weakP,
                                               unsigned long long* __restrict__ strongP,
                                               int* __restrict__ flags,
                                               double w0, double w1, double w2) {
    __shared__ double ldsA[HBH * HBW];    // hblur; reused for mag (MGH*MGW <= HBH*HBW)
    __shared__ double ldsB[BLH * BLW];    // blurred

    const int tid = threadIdx.x;
    const int x0  = blockIdx.x * TX;
    const int y0  = blockIdx.y * TY;
    const int b   = blockIdx.z;
    const float* base = x + (size_t)b * 3u * HWP;

    if (blockIdx.x == 0 && blockIdx.y == 0 && b == 0 && tid <= ROUNDS)
        flags[tid] = (tid == 0);          // seed flood-fill round flags

    // S1: hblur into ldsA; slot row r holds hblur of global row reflect(y0+r-4)
    for (int idx = tid; idx < HBH * HBW; idx += 256) {
        int r = idx / HBW, c = idx - r * HBW;
        int gy  = y0 + r - 4;
        int gyr = reflect_idx(gy, HH);
        int gx  = x0 + c - 2;
        const float* rp = base + (size_t)gyr * WW;
        auto gr = [&](int xx) -> double {
            double rr = (double)rp[xx];
            double gg = (double)rp[HWP + xx];
            double bb = (double)rp[2 * HWP + xx];
            return rr * 0.299 + gg * 0.587 + bb * 0.114;
        };
        double s;
        s  = w0 * gr(reflect_idx(gx - 2, WW));
        s += w1 * gr(reflect_idx(gx - 1, WW));
        s += w2 * gr(reflect_idx(gx,     WW));
        s += w1 * gr(reflect_idx(gx + 1, WW));
        s += w0 * gr(reflect_idx(gx + 2, WW));
        ldsA[idx] = s;
    }
    __syncthreads();

    // S2: vblur into ldsB (rows pre-reflected in ldsA -> raw slot reads = reflect pad)
    for (int idx = tid; idx < BLH * BLW; idx += 256) {
        int r = idx / BLW, c = idx - r * BLW;
        double s;
        s  = w0 * ldsA[(r + 0) * HBW + c];
        s += w1 * ldsA[(r + 1) * HBW + c];
        s += w2 * ldsA[(r + 2) * HBW + c];
        s += w1 * ldsA[(r + 3) * HBW + c];
        s += w0 * ldsA[(r + 4) * HBW + c];
        ldsB[idx] = s;
    }
    __syncthreads();

    // S3: sobel magnitude into ldsA (0 for out-of-image slots = NMS zero pad)
    for (int idx = tid; idx < MGH * MGW; idx += 256) {
        int r = idx / MGW, c = idx - r * MGW;
        int gy = y0 + r - 1, gx = x0 + c - 1;
        double mg = 0.0;
        if (gy >= 0 && gy < HH && gx >= 0 && gx < WW) {
            int ym = gy > 0 ? gy - 1 : 0, yp = gy < HH - 1 ? gy + 1 : HH - 1;
            int xm = gx > 0 ? gx - 1 : 0, xp = gx < WW - 1 ? gx + 1 : WW - 1;
            auto B = [&](int yy, int xx) -> double {
                return ldsB[(yy - y0 + 2) * BLW + (xx - x0 + 2)];
            };
            double b00 = B(ym, xm), b01 = B(ym, gx), b02 = B(ym, xp);
            double b10 = B(gy, xm),                  b12 = B(gy, xp);
            double b20 = B(yp, xm), b21 = B(yp, gx), b22 = B(yp, xp);
            double gxv = -b00 + b02 - 2.0 * b10 + 2.0 * b12 - b20 + b22;
            double gyv = -b00 - 2.0 * b01 - b02 + b20 + 2.0 * b21 + b22;
            mg = sqrt(gxv * gxv + gyv * gyv + 1e-6);
        }
        ldsA[r * MGW + c] = mg;
    }
    __syncthreads();

    // S4: dir (recomputed at center) + NMS + thresholds + ballot to bitplanes
    for (int k = 0; k < (TX * TY) / 256; ++k) {
        int idx = k * 256 + tid;
        int r = idx >> 6, c = idx & 63;   // one wave = one 64px row-word
        int gy = y0 + r, gx = x0 + c;
        int ym = gy > 0 ? gy - 1 : 0, yp = gy < HH - 1 ? gy + 1 : HH - 1;
        int xm = gx > 0 ? gx - 1 : 0, xp = gx < WW - 1 ? gx + 1 : WW - 1;
        auto B = [&](int yy, int xx) -> double {
            return ldsB[(yy - y0 + 2) * BLW + (xx - x0 + 2)];
        };
        double b00 = B(ym, xm), b01 = B(ym, gx), b02 = B(ym, xp);
        double b10 = B(gy, xm),                  b12 = B(gy, xp);
        double b20 = B(yp, xm), b21 = B(yp, gx), b22 = B(yp, xp);
        double gxv = -b00 + b02 - 2.0 * b10 + 2.0 * b12 - b20 + b22;
        double gyv = -b00 - 2.0 * b01 - b02 + b20 + 2.0 * b21 + b22;
        double a = atan2(gyv, gxv) * 57.29577951308232;  // *(180/pi), f64
        a = a / 45.0;
        int ai = (int)rint(a);
        int p = (ai + 8) & 7;
        int dr = ((425   >> (2 * p)) & 3) - 1;
        int dc = ((36890 >> (2 * p)) & 3) - 1;
        double ctr = ldsA[(r + 1) * MGW + (c + 1)];
        double mp  = ldsA[(r + 1 + dr) * MGW + (c + 1 + dc)];
        double mn  = ldsA[(r + 1 - dr) * MGW + (c + 1 - dc)];
        bool ismax = ((ctr - mp) > 0.0) && ((ctr - mn) > 0.0);
        double sm = ismax ? ctr : 0.0;
        out0[(size_t)b * HWP + (size_t)gy * WW + gx] = (float)sm;
        bool strong = (sm > 0.2);
        bool weak   = (sm > 0.1) && !strong;
        unsigned long long wb = __ballot(weak);
        unsigned long long sb = __ballot(strong);
        if ((tid & 63) == 0) {
            int word = gy * WPR + (x0 >> 6);
            weakP[(size_t)b * PW + word]   = wb;
            strongP[(size_t)b * PW + word] = sb;
        }
    }
}

// ---------------- hysteresis: bitplane flood fill, full-height column strips ----------------
__device__ __forceinline__ unsigned long long ks_fill(unsigned long long g, unsigned long long p) {
    unsigned long long q;
    q = p;        g |= q & (g << 1);
    q &= q << 1;  g |= q & (g << 2);
    q &= q << 2;  g |= q & (g << 4);
    q &= q << 4;  g |= q & (g << 8);
    q &= q << 8;  g |= q & (g << 16);
    q &= q << 16; g |= q & (g << 32);
    q = p;        g |= q & (g >> 1);
    q &= q >> 1;  g |= q & (g >> 2);
    q &= q >> 2;  g |= q & (g >> 4);
    q &= q >> 4;  g |= q & (g >> 8);
    q &= q >> 8;  g |= q & (g >> 16);
    q &= q >> 16; g |= q & (g >> 32);
    return g;
}

__global__ void __launch_bounds__(256) k_pass(const unsigned long long* __restrict__ weakP,
                                              unsigned long long* __restrict__ strongP,
                                              int* __restrict__ flags, int rr) {
    __shared__ unsigned long long sp[HH + 2];   // spread-form strong rows (+zero halo)
    __shared__ int s_changed;

    if (flags[rr - 1] == 0) return;             // previous round globally quiet

    const int tid = threadIdx.x;
    const int blk = blockIdx.x;                 // 64 blocks: b(2b) | tx(4b); strip 64w x 1024h
    const int b  = blk >> 4;
    const int tx = blk & 15;
    const unsigned long long* wp = weakP + (size_t)b * PW;
    unsigned long long* spl      = strongP + (size_t)b * PW;
    const int r0 = tid * 4;

    unsigned long long w[4], s[4], ho[4];
    for (int i = 0; i < 4; ++i) {
        int row = r0 + i, wi = row * WPR + tx;
        w[i] = wp[wi];
        s[i] = spl[wi];
        unsigned long long h = 0;               // static horizontal halo from adjacent strips
        if (tx > 0)       h |= spl[wi - 1] >> 63;
        if (tx < WPR - 1) h |= spl[wi + 1] << 63;
        ho[i] = h;
        sp[row + 1] = (s[i] << 1) | s[i] | (s[i] >> 1) | h;
    }
    if (tid == 0) { sp[0] = 0; sp[HH + 1] = 0; }

    auto spread = [&](int i) -> unsigned long long {
        return (s[i] << 1) | s[i] | (s[i] >> 1) | ho[i];
    };

    int blockChanged = 0;
    for (;;) {
        __syncthreads();                        // (A) sp writes visible
        if (tid == 0) s_changed = 0;
        int ch = 0;
        unsigned long long up = sp[r0];         // down sweep (Gauss-Seidel in-thread)
        for (int i = 0; i < 4; ++i) {
            unsigned long long dn = (i < 3) ? spread(i + 1) : sp[r0 + 5];
            unsigned long long g = s[i] | (w[i] & (up | spread(i) | dn));
            g = ks_fill(g, w[i]);
            if (g != s[i]) { s[i] = g; ch = 1; }
            up = spread(i);
        }
        unsigned long long dn2 = sp[r0 + 5];    // up sweep
        for (int i = 3; i >= 0; --i) {
            unsigned long long upv = (i > 0) ? spread(i - 1) : sp[r0];
            unsigned long long g = s[i] | (w[i] & (upv | spread(i) | dn2));
            g = ks_fill(g, w[i]);
            if (g != s[i]) { s[i] = g; ch = 1; }
            dn2 = spread(i);
        }
        __syncthreads();                        // (B) reads done; reset visible
        if (ch) {
            for (int i = 0; i < 4; ++i) sp[r0 + i + 1] = spread(i);
            s_changed = 1;                      // benign race: all writers store 1
        }
        __syncthreads();                        // (C) writes + flag visible
        if (!s_changed) break;
        blockChanged = 1;
    }

    if (blockChanged) {
        for (int i = 0; i < 4; ++i) spl[(r0 + i) * WPR + tx] = s[i];
        if (tid == 0) atomicOr(&flags[rr], 1);  // device-scope by default
    }
}

__global__ void k_edges(const unsigned long long* __restrict__ strongP, float* __restrict__ out1) {
    int i = blockIdx.x * blockDim.x + threadIdx.x;
    if (i >= NPIX) return;
    out1[i] = ((strongP[i >> 6] >> (i & 63)) & 1ull) ? 1.0f : 0.0f;
}

extern "C" void kernel_launch(void* const* d_in, const int* in_sizes, int n_in,
                              void* d_out, int out_size, void* d_ws, size_t ws_size,
                              hipStream_t stream) {
    const float* x = (const float*)d_in[0];
    float* out0 = (float*)d_out;          // suppressed magnitude [4,1,1024,1024]
    float* out1 = out0 + NPIX;            // edges [4,1,1024,1024]

    // workspace: weakP | strongP | flags
    unsigned long long* weakP   = (unsigned long long*)d_ws;
    unsigned long long* strongP = weakP + (size_t)BB * PW;
    int* flags = (int*)(strongP + (size_t)BB * PW);

    // gaussian weights, f64 ops mirroring the reference
    double g0 = exp(-2.0), g1 = exp(-0.5), g2 = 1.0;
    double sum = (((g0 + g1) + g2) + g1) + g0;
    double w0 = g0 / sum, w1 = g1 / sum, w2 = g2 / sum;

    k_front<<<dim3(WW / TX, HH / TY, BB), dim3(256), 0, stream>>>(
        x, out0, weakP, strongP, flags, w0, w1, w2);

    for (int r = 1; r <= ROUNDS; ++r)
        k_pass<<<dim3(BB * WPR), dim3(256), 0, stream>>>(weakP, strongP, flags, r);

    k_edges<<<dim3(NPIX / 256), dim3(256), 0, stream>>>(strongP, out1);
}

// Round 6
// 175.700 us; speedup vs baseline: 2.0693x; 1.0569x over previous
//
#include <hip/hip_runtime.h>
#include <math.h>

static constexpr int BB  = 4;
static constexpr int HH  = 1024;
static constexpr int WW  = 1024;
static constexpr int HWP = HH * WW;       // 1<<20
static constexpr int NPIX = BB * HWP;     // 4<<20
static constexpr int WPR = WW / 64;       // 16 words per image row
static constexpr int PW  = HWP / 64;      // 16384 words per image bitplane
static constexpr int ROUNDS = 8;

// fused-stencil tile: 64 wide x 32 tall output
static constexpr int TX = 64, TY = 32;
// LDS region shapes (rows x cols):
//   gray  : 40 x 72  (y0-4..y0+35 reflected, x0-4..x0+67 reflected)   -> array A
//   hblur : 40 x 68  (cols x0-2..x0+65)                               -> array B
//   vblur : 36 x 68  (rows y0-2..y0+33)                               -> array A (gray dead)
//   mag   : 34 x 66  (rows y0-1..y0+32, cols x0-1..x0+64)             -> array B (hblur dead)
//   dirp  : 32 x 64  center only                                       -> array P (u8)
static constexpr int GH = 40, GW = 72;
static constexpr int HBH = 40, HBW = 68;
static constexpr int VBH = 36, VBW = 68;
static constexpr int MGH = 34, MGW = 66;

__device__ __forceinline__ int reflect_idx(int i, int n) {
    i = (i < 0) ? -i : i;                 // jnp.pad mode='reflect': -1 -> 1
    return (i >= n) ? (2 * n - 2 - i) : i;
}

// ---------- fused: gray -> hblur -> vblur -> sobel/mag -> dir -> NMS -> ballot ----------
__global__ void __launch_bounds__(256) k_front(const float* __restrict__ x,
                                               float* __restrict__ out0,
                                               unsigned long long* __restrict__ weakP,
                                               unsigned long long* __restrict__ strongP,
                                               int* __restrict__ flags,
                                               double w0, double w1, double w2) {
    __shared__ double A[GH * GW];         // gray, then vblur
    __shared__ double B[HBH * HBW];       // hblur, then mag
    __shared__ unsigned char P[TY * TX];  // quantized direction, center pixels

    const int tid = threadIdx.x;
    const int x0  = blockIdx.x * TX;
    const int y0  = blockIdx.y * TY;
    const int b   = blockIdx.z;
    const float* base = x + (size_t)b * 3u * HWP;

    if (blockIdx.x == 0 && blockIdx.y == 0 && b == 0 && tid <= ROUNDS)
        flags[tid] = (tid == 0);          // seed flood-fill round flags

    // S1: grayscale into A (rows/cols pre-reflected so later reads are raw)
    for (int idx = tid; idx < GH * GW; idx += 256) {
        int r = idx / GW, c = idx - r * GW;
        int gyr = reflect_idx(y0 + r - 4, HH);
        int gxr = reflect_idx(x0 + c - 4, WW);
        const float* rp = base + (size_t)gyr * WW;
        double rr = (double)rp[gxr];
        double gg = (double)rp[HWP + gxr];
        double bb = (double)rp[2 * HWP + gxr];
        A[idx] = rr * 0.299 + gg * 0.587 + bb * 0.114;
    }
    __syncthreads();

    // S2: hblur into B (gray slot col j = c + d + 2, d = -2..2 -> j = c..c+4)
    for (int idx = tid; idx < HBH * HBW; idx += 256) {
        int r = idx / HBW, c = idx - r * HBW;
        const double* g = &A[r * GW + c];
        double s;
        s  = w0 * g[0];
        s += w1 * g[1];
        s += w2 * g[2];
        s += w1 * g[3];
        s += w0 * g[4];
        B[idx] = s;
    }
    __syncthreads();

    // S3: vblur into A (hblur slot rows r..r+4 = gy-2..gy+2, pre-reflected)
    for (int idx = tid; idx < VBH * VBW; idx += 256) {
        int r = idx / VBW, c = idx - r * VBW;
        const double* h = &B[r * HBW + c];
        double s;
        s  = w0 * h[0];
        s += w1 * h[1 * HBW];
        s += w2 * h[2 * HBW];
        s += w1 * h[3 * HBW];
        s += w0 * h[4 * HBW];
        A[idx] = s;
    }
    __syncthreads();

    // S4: sobel magnitude into B (0 outside image = NMS zero pad) + dir bytes for center
    for (int idx = tid; idx < MGH * MGW; idx += 256) {
        int r = idx / MGW, c = idx - r * MGW;
        int gy = y0 + r - 1, gx = x0 + c - 1;
        double mg = 0.0;
        if (gy >= 0 && gy < HH && gx >= 0 && gx < WW) {
            int ym = gy > 0 ? gy - 1 : 0, yp = gy < HH - 1 ? gy + 1 : HH - 1;
            int xm = gx > 0 ? gx - 1 : 0, xp = gx < WW - 1 ? gx + 1 : WW - 1;
            auto BL = [&](int yy, int xx) -> double {
                return A[(yy - y0 + 2) * VBW + (xx - x0 + 2)];
            };
            double b00 = BL(ym, xm), b01 = BL(ym, gx), b02 = BL(ym, xp);
            double b10 = BL(gy, xm),                   b12 = BL(gy, xp);
            double b20 = BL(yp, xm), b21 = BL(yp, gx), b22 = BL(yp, xp);
            double gxv = -b00 + b02 - 2.0 * b10 + 2.0 * b12 - b20 + b22;
            double gyv = -b00 - 2.0 * b01 - b02 + b20 + 2.0 * b21 + b22;
            mg = sqrt(gxv * gxv + gyv * gyv + 1e-6);
            if (r >= 1 && r < 33 && c >= 1 && c < 65) {
                // octant classification == round(atan2(gy,gx)*4/pi) mod 8, boundary-exact
                double ax = fabs(gxv), ay = fabs(gyv);
                int p;
                if (ay < 0.41421356237309503 * ax)       // tan(22.5deg)
                    p = (gxv >= 0.0) ? 0 : 4;
                else if (ay < 2.4142135623730951 * ax)   // tan(67.5deg)
                    p = (gyv >= 0.0) ? ((gxv >= 0.0) ? 1 : 3)
                                     : ((gxv >= 0.0) ? 7 : 5);
                else
                    p = (gyv >= 0.0) ? 2 : 6;
                P[(r - 1) * TX + (c - 1)] = (unsigned char)p;
            }
        }
        B[r * MGW + c] = mg;
    }
    __syncthreads();

    // S5: NMS + thresholds + ballot (one wave = one 64px row-word)
    for (int k = 0; k < (TX * TY) / 256; ++k) {
        int idx = k * 256 + tid;
        int r = idx >> 6, c = idx & 63;
        double ctr = B[(r + 1) * MGW + (c + 1)];
        int p = P[idx];
        int dr = ((425   >> (2 * p)) & 3) - 1;
        int dc = ((36890 >> (2 * p)) & 3) - 1;
        double mp = B[(r + 1 + dr) * MGW + (c + 1 + dc)];
        double mn = B[(r + 1 - dr) * MGW + (c + 1 - dc)];
        bool ismax = ((ctr - mp) > 0.0) && ((ctr - mn) > 0.0);
        double sm = ismax ? ctr : 0.0;
        out0[(size_t)b * HWP + (size_t)(y0 + r) * WW + (x0 + c)] = (float)sm;
        bool strong = (sm > 0.2);
        bool weak   = (sm > 0.1) && !strong;
        unsigned long long wb = __ballot(weak);
        unsigned long long sb = __ballot(strong);
        if ((tid & 63) == 0) {
            int word = (y0 + r) * WPR + (x0 >> 6);
            weakP[(size_t)b * PW + word]   = wb;
            strongP[(size_t)b * PW + word] = sb;
        }
    }
}

// ---------------- hysteresis: bitplane flood fill, full-height column strips ----------------
__device__ __forceinline__ unsigned long long ks_fill(unsigned long long g, unsigned long long p) {
    unsigned long long q;
    q = p;        g |= q & (g << 1);
    q &= q << 1;  g |= q & (g << 2);
    q &= q << 2;  g |= q & (g << 4);
    q &= q << 4;  g |= q & (g << 8);
    q &= q << 8;  g |= q & (g << 16);
    q &= q << 16; g |= q & (g << 32);
    q = p;        g |= q & (g >> 1);
    q &= q >> 1;  g |= q & (g >> 2);
    q &= q >> 2;  g |= q & (g >> 4);
    q &= q >> 4;  g |= q & (g >> 8);
    q &= q >> 8;  g |= q & (g >> 16);
    q &= q >> 16; g |= q & (g >> 32);
    return g;
}

__global__ void __launch_bounds__(256) k_pass(const unsigned long long* __restrict__ weakP,
                                              unsigned long long* __restrict__ strongP,
                                              int* __restrict__ flags, int rr) {
    __shared__ unsigned long long sp[HH + 2];   // spread-form strong rows (+zero halo)
    __shared__ int s_changed;

    if (flags[rr - 1] == 0) return;             // previous round globally quiet

    const int tid = threadIdx.x;
    const int blk = blockIdx.x;                 // 64 blocks: b(2b) | tx(4b); strip 64w x 1024h
    const int b  = blk >> 4;
    const int tx = blk & 15;
    const unsigned long long* wp = weakP + (size_t)b * PW;
    unsigned long long* spl      = strongP + (size_t)b * PW;
    const int r0 = tid * 4;

    unsigned long long w[4], s[4], ho[4];
    for (int i = 0; i < 4; ++i) {
        int row = r0 + i, wi = row * WPR + tx;
        w[i] = wp[wi];
        s[i] = spl[wi];
        unsigned long long h = 0;               // static horizontal halo from adjacent strips
        if (tx > 0)       h |= spl[wi - 1] >> 63;
        if (tx < WPR - 1) h |= spl[wi + 1] << 63;
        ho[i] = h;
        sp[row + 1] = (s[i] << 1) | s[i] | (s[i] >> 1) | h;
    }
    if (tid == 0) { sp[0] = 0; sp[HH + 1] = 0; }

    auto spread = [&](int i) -> unsigned long long {
        return (s[i] << 1) | s[i] | (s[i] >> 1) | ho[i];
    };

    int blockChanged = 0;
    for (;;) {
        __syncthreads();                        // (A) sp writes visible
        if (tid == 0) s_changed = 0;
        int ch = 0;
        unsigned long long up = sp[r0];         // down sweep (Gauss-Seidel in-thread)
        for (int i = 0; i < 4; ++i) {
            unsigned long long dn = (i < 3) ? spread(i + 1) : sp[r0 + 5];
            unsigned long long g = s[i] | (w[i] & (up | spread(i) | dn));
            g = ks_fill(g, w[i]);
            if (g != s[i]) { s[i] = g; ch = 1; }
            up = spread(i);
        }
        unsigned long long dn2 = sp[r0 + 5];    // up sweep
        for (int i = 3; i >= 0; --i) {
            unsigned long long upv = (i > 0) ? spread(i - 1) : sp[r0];
            unsigned long long g = s[i] | (w[i] & (upv | spread(i) | dn2));
            g = ks_fill(g, w[i]);
            if (g != s[i]) { s[i] = g; ch = 1; }
            dn2 = spread(i);
        }
        __syncthreads();                        // (B) reads done; reset visible
        if (ch) {
            for (int i = 0; i < 4; ++i) sp[r0 + i + 1] = spread(i);
            s_changed = 1;                      // benign race: all writers store 1
        }
        __syncthreads();                        // (C) writes + flag visible
        if (!s_changed) break;
        blockChanged = 1;
    }

    if (blockChanged) {
        for (int i = 0; i < 4; ++i) spl[(r0 + i) * WPR + tx] = s[i];
        if (tid == 0) atomicOr(&flags[rr], 1);  // device-scope by default
    }
}

__global__ void k_edges(const unsigned long long* __restrict__ strongP, float* __restrict__ out1) {
    int i = blockIdx.x * blockDim.x + threadIdx.x;
    if (i >= NPIX) return;
    out1[i] = ((strongP[i >> 6] >> (i & 63)) & 1ull) ? 1.0f : 0.0f;
}

extern "C" void kernel_launch(void* const* d_in, const int* in_sizes, int n_in,
                              void* d_out, int out_size, void* d_ws, size_t ws_size,
                              hipStream_t stream) {
    const float* x = (const float*)d_in[0];
    float* out0 = (float*)d_out;          // suppressed magnitude [4,1,1024,1024]
    float* out1 = out0 + NPIX;            // edges [4,1,1024,1024]

    // workspace: weakP | strongP | flags
    unsigned long long* weakP   = (unsigned long long*)d_ws;
    unsigned long long* strongP = weakP + (size_t)BB * PW;
    int* flags = (int*)(strongP + (size_t)BB * PW);

    // gaussian weights, f64 ops mirroring the reference
    double g0 = exp(-2.0), g1 = exp(-0.5), g2 = 1.0;
    double sum = (((g0 + g1) + g2) + g1) + g0;
    double w0 = g0 / sum, w1 = g1 / sum, w2 = g2 / sum;

    k_front<<<dim3(WW / TX, HH / TY, BB), dim3(256), 0, stream>>>(
        x, out0, weakP, strongP, flags, w0, w1, w2);

    for (int r = 1; r <= ROUNDS; ++r)
        k_pass<<<dim3(BB * WPR), dim3(256), 0, stream>>>(weakP, strongP, flags, r);

    k_edges<<<dim3(NPIX / 256), dim3(256), 0, stream>>>(strongP, out1);
}